// Round 13
// baseline (106.902 us; speedup 1.0000x reference)
//
#include <hip/hip_runtime.h>
#include <hip/hip_bf16.h>

typedef __attribute__((ext_vector_type(8))) short bf16x8;
typedef __attribute__((ext_vector_type(4))) float f32x4;
typedef unsigned short u16;
typedef unsigned int u32;

__device__ __forceinline__ u32 bfr(float x) {
  u32 u = __float_as_uint(x);
  return (u + 0x7fffu + ((u >> 16) & 1u)) >> 16;  // RNE f32 -> bf16 bits
}
__device__ __forceinline__ u32 pk2(float lo, float hi) {
  return bfr(lo) | (bfr(hi) << 16);
}
__device__ __forceinline__ u32 cvtpk(float lo, float hi) {
  u32 r;
  asm("v_cvt_pk_bf16_f32 %0, %1, %2" : "=v"(r) : "v"(lo), "v"(hi));
  return r;
}

__device__ __forceinline__ f32x4 mfma16(bf16x8 a, bf16x8 b, f32x4 c) {
  return __builtin_amdgcn_mfma_f32_16x16x32_bf16(a, b, c, 0, 0, 0);
}

// ------------------------------------------------- combined prep (weights+mask)
__global__ __launch_bounds__(256) void prep_all(
    const float* __restrict__ qkv_w, const float* __restrict__ out_w,
    const float* __restrict__ w1, const float* __restrict__ w2,
    const int* __restrict__ mask,
    u16* __restrict__ qkvT, u16* __restrict__ outT,
    u16* __restrict__ w1T, u16* __restrict__ w2T, int* __restrict__ flag) {
  __shared__ int wbad[4];
  int b = blockIdx.x;
  if (b >= 640) {
    int l = b - 640;
    int bad = 0;
    for (int i = threadIdx.x; i < 2048; i += 256)
      bad |= (mask[l * 2048 + i] != 1);
    unsigned long long bl = __ballot(bad != 0);
    if ((threadIdx.x & 63) == 0) wbad[threadIdx.x >> 6] = (bl != 0ULL) ? 1 : 0;
    __syncthreads();
    if (threadIdx.x == 0)
      flag[l] = (wbad[0] | wbad[1] | wbad[2] | wbad[3]) ? 0 : 1;
    return;
  }
  int idx = b * 256 + threadIdx.x;
  if (idx < 49152) {
    int n = idx >> 7, k = idx & 127;
    qkvT[idx] = (u16)bfr(qkv_w[k * 384 + n]);
  } else if (idx < 49152 + 16384) {
    int i = idx - 49152;
    int n = i >> 7, k = i & 127;
    outT[i] = (u16)bfr(out_w[k * 128 + n]);
  } else if (idx < 49152 + 16384 + 49152) {
    int i = idx - 49152 - 16384;
    int n = i >> 7, k = i & 127;
    w1T[i] = (u16)bfr(w1[k * 384 + n]);
  } else if (idx < 163840) {
    int i = idx - 49152 - 16384 - 49152;
    int n = i / 384, k = i - n * 384;
    w2T[i] = (u16)bfr(w2[k * 128 + n]);
  }
}

// ------------------------------------------- wide GEMM: 64 rows x 128 cols
// Structural clone of gemm_ln's proven staging/MFMA core, with col-block n0.
// CONVA: A f32 -> bf16 during staging. EPI 2 = bias+relu bf16 ; EPI 3 = qkv.
template <int K, int N, int EPI, bool CONVA>
__global__ __launch_bounds__(256) void gemm_bf16w(
    const void* __restrict__ Av, const u16* __restrict__ WT,
    const float* __restrict__ bias,
    u16* __restrict__ O0, u16* __restrict__ O1, u16* __restrict__ O2) {
  __shared__ u16 lds_a[64 * 136];
  __shared__ u16 lds_b[128 * 136];
  const int m0 = blockIdx.x * 64, n0 = blockIdx.y * 128;
  const int tid = threadIdx.x, lane = tid & 63, wv = tid >> 6;
  const int c = lane & 15, g = lane >> 4;

  f32x4 acc[8] = {};
  for (int kt = 0; kt < K / 128; ++kt) {
    if (kt) __syncthreads();
    for (int i = tid; i < 1024; i += 256) {
      int row = i >> 4, cc = (i & 15) * 8;
      if constexpr (CONVA) {
        const float* Af = (const float*)Av;
        const float4* pa =
            (const float4*)(Af + (size_t)(m0 + row) * K + kt * 128 + cc);
        float4 v0 = pa[0], v1 = pa[1];
        uint4 aw = {pk2(v0.x, v0.y), pk2(v0.z, v0.w), pk2(v1.x, v1.y),
                    pk2(v1.z, v1.w)};
        *(uint4*)(&lds_a[row * 136 + cc]) = aw;
      } else {
        const u16* Au = (const u16*)Av;
        *(uint4*)(&lds_a[row * 136 + cc]) =
            *(const uint4*)(Au + (size_t)(m0 + row) * K + kt * 128 + cc);
      }
    }
    for (int i = tid; i < 2048; i += 256) {
      int row = i >> 4, cc = (i & 15) * 8;
      *(uint4*)(&lds_b[row * 136 + cc]) =
          *(const uint4*)(WT + (size_t)(n0 + row) * K + kt * 128 + cc);
    }
    __syncthreads();
#pragma unroll
    for (int ks = 0; ks < 4; ++ks) {
      bf16x8 a = *(bf16x8*)(&lds_a[(wv * 16 + c) * 136 + ks * 32 + 8 * g]);
#pragma unroll
      for (int ni = 0; ni < 8; ++ni) {
        bf16x8 b = *(bf16x8*)(&lds_b[(ni * 16 + c) * 136 + ks * 32 + 8 * g]);
        acc[ni] = mfma16(a, b, acc[ni]);
      }
    }
  }
  // epilogue: rows rbase+r ; col n = n0 + ni*16 + c
  const int rbase = m0 + wv * 16 + 4 * g;
#pragma unroll
  for (int ni = 0; ni < 8; ++ni) {
    const int n = n0 + ni * 16 + c;
    if constexpr (EPI == 2) {
      float bv = bias[n];
#pragma unroll
      for (int r = 0; r < 4; ++r)
        O0[(size_t)(rbase + r) * N + n] =
            (u16)bfr(fmaxf(acc[ni][r] + bv, 0.f));
    } else {  // EPI == 3 : qkv (Qs scaled 1/sqrt(32), Kb, Vt transposed)
      const int reg = n >> 7, hh = (n >> 5) & 3, d = n & 31;
      const int l = rbase >> 11, s = rbase & 2047;
      const size_t lh = (size_t)l * 4 + hh;
      if (reg == 0) {
#pragma unroll
        for (int r = 0; r < 4; ++r)
          O0[(lh * 2048 + s + r) * 32 + d] =
              (u16)bfr(acc[ni][r] * 0.17677669529663687f);
      } else if (reg == 1) {
#pragma unroll
        for (int r = 0; r < 4; ++r)
          O1[(lh * 2048 + s + r) * 32 + d] = (u16)bfr(acc[ni][r]);
      } else {
        uint2 w = {pk2(acc[ni][0], acc[ni][1]), pk2(acc[ni][2], acc[ni][3])};
        *(uint2*)(O2 + (lh * 32 + d) * 2048 + s) = w;
      }
    }
  }
}

// ---------------------------------------------- fused GEMM(+bias/relu)+res+LN
template <int K, bool RELU>
__global__ __launch_bounds__(256) void gemm_ln(
    const u16* __restrict__ A, const u16* __restrict__ WT,
    const float* __restrict__ bias, const float* __restrict__ resid,
    const float* __restrict__ gain, const float* __restrict__ lnb,
    float* __restrict__ outf, u16* __restrict__ outb) {
  __shared__ u16 lds_a[64 * 136];
  __shared__ u16 lds_b[128 * 136];
  const int m0 = blockIdx.x * 64;
  const int tid = threadIdx.x, lane = tid & 63, wv = tid >> 6;
  const int c = lane & 15, g = lane >> 4;

  f32x4 acc[8] = {};
  for (int kt = 0; kt < K / 128; ++kt) {
    if (kt) __syncthreads();
    for (int i = tid; i < 1024; i += 256) {
      int row = i >> 4, cc = (i & 15) * 8;
      *(uint4*)(&lds_a[row * 136 + cc]) =
          *(const uint4*)(A + (size_t)(m0 + row) * K + kt * 128 + cc);
    }
    for (int i = tid; i < 2048; i += 256) {
      int row = i >> 4, cc = (i & 15) * 8;
      *(uint4*)(&lds_b[row * 136 + cc]) =
          *(const uint4*)(WT + (size_t)row * K + kt * 128 + cc);
    }
    __syncthreads();
#pragma unroll
    for (int ks = 0; ks < 4; ++ks) {
      bf16x8 a = *(bf16x8*)(&lds_a[(wv * 16 + c) * 136 + ks * 32 + 8 * g]);
#pragma unroll
      for (int ni = 0; ni < 8; ++ni) {
        bf16x8 b = *(bf16x8*)(&lds_b[(ni * 16 + c) * 136 + ks * 32 + 8 * g]);
        acc[ni] = mfma16(a, b, acc[ni]);
      }
    }
  }
  const int rbase = m0 + wv * 16 + 4 * g;
  float gv[8], lb[8], bv[8];
#pragma unroll
  for (int ni = 0; ni < 8; ++ni) {
    gv[ni] = gain[ni * 16 + c];
    lb[ni] = lnb[ni * 16 + c];
    if constexpr (RELU) bv[ni] = bias[ni * 16 + c];
  }
  float t[8][4];
  float sum[4] = {0.f, 0.f, 0.f, 0.f}, sq[4] = {0.f, 0.f, 0.f, 0.f};
#pragma unroll
  for (int ni = 0; ni < 8; ++ni) {
#pragma unroll
    for (int r = 0; r < 4; ++r) {
      float v = acc[ni][r];
      if constexpr (RELU) v = fmaxf(v + bv[ni], 0.f);
      v += resid[(size_t)(rbase + r) * 128 + ni * 16 + c];
      t[ni][r] = v;
      sum[r] += v;
      sq[r] += v * v;
    }
  }
#pragma unroll
  for (int off = 1; off < 16; off <<= 1) {
#pragma unroll
    for (int r = 0; r < 4; ++r) {
      sum[r] += __shfl_xor(sum[r], off);
      sq[r] += __shfl_xor(sq[r], off);
    }
  }
#pragma unroll
  for (int r = 0; r < 4; ++r) {
    float mean = sum[r] * (1.0f / 128.0f);
    float var = sq[r] * (1.0f / 128.0f) - mean * mean;
    float inv = rsqrtf(var + 1e-5f);
#pragma unroll
    for (int ni = 0; ni < 8; ++ni) {
      float o = gv[ni] * (t[ni][r] - mean) * inv + lb[ni];
      outf[(size_t)(rbase + r) * 128 + ni * 16 + c] = o;
      if (outb) outb[(size_t)(rbase + r) * 128 + ni * 16 + c] = (u16)bfr(o);
    }
  }
}

// ---------------------------------------------------------------- attention
// R11 attn4 + MINIMAL R8-proven accL delta. P stays ARRAY-then-pack
// (empirical rule: inline P pack fails -- R5/R9/R10/R12; array pack passes --
// R4/R6/R7/R8/R11). Sequential max chain kept verbatim from R11.
__global__ __launch_bounds__(256) void attn4(
    const u16* __restrict__ Qs, const u16* __restrict__ Kb,
    const u16* __restrict__ Vt, const int* __restrict__ mask,
    const int* __restrict__ mflag, u16* __restrict__ ctx) {
  __shared__ u16 lds_k[2][64 * 40];   // [key][d]
  __shared__ u16 lds_vt[2][32 * 72];  // [d][key]
  __shared__ u16 lds_p[4][16 * 72];   // per-wave P [q][key 0..63] stride 72
  __shared__ float lds_mk[2][64];

  const int bid = blockIdx.x;
  const int qt = bid & 31, lh = bid >> 5;
  const int tid = threadIdx.x, lane = tid & 63, wv = tid >> 6;
  const int c = lane & 15, g = lane >> 4;
  const int tok0 = (lh >> 2) * 2048;
  const int h = lh & 3;
  const int allone = mflag[lh >> 2];

  const int qrow = qt * 64 + wv * 16 + c;
  const bf16x8 qf = *(const bf16x8*)(Qs + ((size_t)lh * 2048 + qrow) * 32 + 8 * g);
  const float mq = allone ? 1.0f : (float)mask[tok0 + qrow];

  const int kr_ = tid & 63, kc_ = tid >> 6;  // K stage: row, 16B chunk
  const int vr_ = tid >> 3, vc_ = tid & 7;   // V stage: row(d), 16B chunk
  const u16* kbase = Kb + ((size_t)lh * 2048) * 32 + kr_ * 32 + kc_ * 8;
  const u16* vbase = Vt + ((size_t)lh * 32 + vr_) * 2048 + vc_ * 8;

  uint4 krg, vrg;
  float mkv = 0.f;
  auto issue = [&](int kt0) {
    krg = *(const uint4*)(kbase + (size_t)kt0 * 32);
    vrg = *(const uint4*)(vbase + kt0);
    if (!allone && tid < 64) mkv = (float)mask[tok0 + kt0 + tid];
  };
  auto commit = [&](int buf) {
    *(uint4*)(&lds_k[buf][kr_ * 40 + kc_ * 8]) = krg;
    *(uint4*)(&lds_vt[buf][vr_ * 72 + vc_ * 8]) = vrg;
    if (!allone && tid < 64) lds_mk[buf][tid] = mkv;
  };

  issue(0);
  commit(0);
  __syncthreads();

  f32x4 acc0 = {0.f, 0.f, 0.f, 0.f}, acc1 = {0.f, 0.f, 0.f, 0.f};
  f32x4 accL = {0.f, 0.f, 0.f, 0.f};
  float m_run = -1e30f;
  const f32x4 zf = {0.f, 0.f, 0.f, 0.f};
  union { u32 u[4]; bf16x8 v; } onesU;
  onesU.u[0] = onesU.u[1] = onesU.u[2] = onesU.u[3] = 0x3F803F80u;
  const bf16x8 onesA = onesU.v;

  for (int t = 0; t < 32; ++t) {
    const int cur = t & 1;
    if (t < 31) issue((t + 1) * 64);

    // QK^T -> S^T (row=key via reg, col=q via lane)
    f32x4 s[4];
#pragma unroll
    for (int j = 0; j < 4; ++j) {
      bf16x8 a = *(bf16x8*)(&lds_k[cur][(16 * j + c) * 40 + 8 * g]);
      s[j] = mfma16(a, qf, zf);
    }
    // faithful mask: am*sc + (am-1)*(-1e9)  -- NO algebraic refactor:
    // (sc-1e9)+1e9 quantizes sc to f32-ulp(1e9)=64 (round-3 bug).
    float sv[16];
    if (allone) {
#pragma unroll
      for (int j = 0; j < 4; ++j)
#pragma unroll
        for (int r = 0; r < 4; ++r) sv[4 * j + r] = s[j][r];
    } else {
#pragma unroll
      for (int j = 0; j < 4; ++j) {
        float4 mk4 = *(float4*)(&lds_mk[cur][16 * j + 4 * g]);  // broadcast
        const float* mkp = (const float*)&mk4;
#pragma unroll
        for (int r = 0; r < 4; ++r) {
          float am = mq * mkp[r];
          sv[4 * j + r] = am * s[j][r] + (am - 1.0f) * (-1e9f);
        }
      }
    }
    float tmax = sv[0];
#pragma unroll
    for (int i = 1; i < 16; ++i) tmax = fmaxf(tmax, sv[i]);
    tmax = fmaxf(tmax, __shfl_xor(tmax, 16));
    tmax = fmaxf(tmax, __shfl_xor(tmax, 32));
    if (!__all(tmax <= m_run + 8.0f)) {  // defer-max (T13)
      float mnew = fmaxf(m_run, tmax);
      float corr = __expf(m_run - mnew);
      m_run = mnew;
      accL *= corr;
      acc0 *= corr;
      acc1 *= corr;
    }
    // p ARRAY first (proven form), THEN separate pack loop
    float p[16];
#pragma unroll
    for (int i = 0; i < 16; ++i) p[i] = __expf(sv[i] - m_run);
#pragma unroll
    for (int j = 0; j < 4; ++j) {
      uint2 w = {cvtpk(p[4 * j], p[4 * j + 1]), cvtpk(p[4 * j + 2], p[4 * j + 3])};
      *(uint2*)(&lds_p[wv][c * 72 + 16 * j + 4 * g]) = w;
    }
    bf16x8 pb0 = *(bf16x8*)(&lds_p[wv][c * 72 + 8 * g]);
    bf16x8 pb1 = *(bf16x8*)(&lds_p[wv][c * 72 + 32 + 8 * g]);
    bf16x8 v00 = *(bf16x8*)(&lds_vt[cur][c * 72 + 8 * g]);
    bf16x8 v01 = *(bf16x8*)(&lds_vt[cur][c * 72 + 32 + 8 * g]);
    bf16x8 v10 = *(bf16x8*)(&lds_vt[cur][(16 + c) * 72 + 8 * g]);
    bf16x8 v11 = *(bf16x8*)(&lds_vt[cur][(16 + c) * 72 + 32 + 8 * g]);
    acc0 = mfma16(v00, pb0, acc0);
    acc0 = mfma16(v01, pb1, acc0);
    acc1 = mfma16(v10, pb0, acc1);
    acc1 = mfma16(v11, pb1, acc1);
    accL = mfma16(onesA, pb0, accL);  // lsum[q=c] = col-sum of P (R8-proven)
    accL = mfma16(onesA, pb1, accL);

    if (t < 31) commit(cur ^ 1);
    __syncthreads();
  }
  float inv = 1.0f / accL[0];
  u16* op = ctx + (size_t)(tok0 + qrow) * 128 + h * 32;
  uint2 o0 = {cvtpk(acc0[0] * inv, acc0[1] * inv),
              cvtpk(acc0[2] * inv, acc0[3] * inv)};
  uint2 o1 = {cvtpk(acc1[0] * inv, acc1[1] * inv),
              cvtpk(acc1[2] * inv, acc1[3] * inv)};
  *(uint2*)(op + 4 * g) = o0;
  *(uint2*)(op + 16 + 4 * g) = o1;
}

// ---------------------------------------------------------------- launch
extern "C" void kernel_launch(void* const* d_in, const int* in_sizes, int n_in,
                              void* d_out, int out_size, void* d_ws,
                              size_t ws_size, hipStream_t stream) {
  (void)in_sizes; (void)n_in; (void)out_size; (void)ws_size;
  const float* x = (const float*)d_in[0];
  const int* mask = (const int*)d_in[1];
  const float* qkv_w = (const float*)d_in[2];
  const float* out_w = (const float*)d_in[3];
  const float* w1 = (const float*)d_in[4];
  const float* b1 = (const float*)d_in[5];
  const float* w2 = (const float*)d_in[6];
  const float* b2 = (const float*)d_in[7];
  const float* g1 = (const float*)d_in[8];
  const float* be1 = (const float*)d_in[9];
  const float* g2 = (const float*)d_in[10];
  const float* be2 = (const float*)d_in[11];
  float* out = (float*)d_out;

  char* ws = (char*)d_ws;
  const size_t MB = 1 << 20;
  // [0,12): Qs|Kb|Vt ; after attn reused as ff_bf (exactly 12 MB)
  u16* Qs = (u16*)(ws);
  u16* Kb = (u16*)(ws + 4 * MB);
  u16* Vt = (u16*)(ws + 8 * MB);
  u16* ff_bf = (u16*)(ws);
  u16* ctx_bf = (u16*)(ws + 12 * MB);  // [12,16)
  float* h = (float*)(ws + 16 * MB);   // [16,24)
  u16* h_bf = (u16*)(ws + 24 * MB);    // [24,28)
  u16* qkvT = (u16*)(ws + 32 * MB);
  u16* outT = qkvT + 384 * 128;
  u16* w1T = outT + 128 * 128;
  u16* w2T = w1T + 384 * 128;
  int* mflag = (int*)(ws + 33 * MB);

  prep_all<<<648, 256, 0, stream>>>(qkv_w, out_w, w1, w2, mask, qkvT, outT,
                                    w1T, w2T, mflag);
  gemm_bf16w<128, 384, 3, true><<<dim3(256, 3), 256, 0, stream>>>(
      (const void*)x, qkvT, nullptr, Qs, Kb, Vt);
  attn4<<<1024, 256, 0, stream>>>(Qs, Kb, Vt, mask, mflag, ctx_bf);
  gemm_ln<128, false><<<256, 256, 0, stream>>>(
      ctx_bf, outT, nullptr, x, g1, be1, h, h_bf);
  gemm_bf16w<128, 384, 2, false><<<dim3(256, 3), 256, 0, stream>>>(
      (const void*)h_bf, w1T, b1, ff_bf, nullptr, nullptr);
  gemm_ln<384, true><<<256, 256, 0, stream>>>(
      ff_bf, w2T, b2, h, g2, be2, out, nullptr);
}

// Round 14
// 106.297 us; speedup vs baseline: 1.0057x; 1.0057x over previous
//
#include <hip/hip_runtime.h>
#include <hip/hip_bf16.h>

typedef __attribute__((ext_vector_type(8))) short bf16x8;
typedef __attribute__((ext_vector_type(4))) float f32x4;
typedef unsigned short u16;
typedef unsigned int u32;

__device__ __forceinline__ u32 bfr(float x) {
  u32 u = __float_as_uint(x);
  return (u + 0x7fffu + ((u >> 16) & 1u)) >> 16;  // RNE f32 -> bf16 bits
}
__device__ __forceinline__ u32 pk2(float lo, float hi) {
  return bfr(lo) | (bfr(hi) << 16);
}
__device__ __forceinline__ u32 cvtpk(float lo, float hi) {
  u32 r;
  asm("v_cvt_pk_bf16_f32 %0, %1, %2" : "=v"(r) : "v"(lo), "v"(hi));
  return r;
}

__device__ __forceinline__ f32x4 mfma16(bf16x8 a, bf16x8 b, f32x4 c) {
  return __builtin_amdgcn_mfma_f32_16x16x32_bf16(a, b, c, 0, 0, 0);
}

// ------------------------------------------------- combined prep (weights+mask)
__global__ __launch_bounds__(256) void prep_all(
    const float* __restrict__ qkv_w, const float* __restrict__ out_w,
    const float* __restrict__ w1, const float* __restrict__ w2,
    const int* __restrict__ mask,
    u16* __restrict__ qkvT, u16* __restrict__ outT,
    u16* __restrict__ w1T, u16* __restrict__ w2T, int* __restrict__ flag) {
  __shared__ int wbad[4];
  int b = blockIdx.x;
  if (b >= 640) {
    int l = b - 640;
    int bad = 0;
    for (int i = threadIdx.x; i < 2048; i += 256)
      bad |= (mask[l * 2048 + i] != 1);
    unsigned long long bl = __ballot(bad != 0);
    if ((threadIdx.x & 63) == 0) wbad[threadIdx.x >> 6] = (bl != 0ULL) ? 1 : 0;
    __syncthreads();
    if (threadIdx.x == 0)
      flag[l] = (wbad[0] | wbad[1] | wbad[2] | wbad[3]) ? 0 : 1;
    return;
  }
  int idx = b * 256 + threadIdx.x;
  if (idx < 49152) {
    int n = idx >> 7, k = idx & 127;
    qkvT[idx] = (u16)bfr(qkv_w[k * 384 + n]);
  } else if (idx < 49152 + 16384) {
    int i = idx - 49152;
    int n = i >> 7, k = i & 127;
    outT[i] = (u16)bfr(out_w[k * 128 + n]);
  } else if (idx < 49152 + 16384 + 49152) {
    int i = idx - 49152 - 16384;
    int n = i >> 7, k = i & 127;
    w1T[i] = (u16)bfr(w1[k * 384 + n]);
  } else if (idx < 163840) {
    int i = idx - 49152 - 16384 - 49152;
    int n = i / 384, k = i - n * 384;
    w2T[i] = (u16)bfr(w2[k * 128 + n]);
  }
}

// ---------------------------------------------------------------- generic GEMM
// R11-exact. CONVA: A f32 -> bf16 during staging. EPI 2 = bias+relu bf16 ;
// EPI 3 = qkv epilogue (Qs scaled by 1/sqrt(32), Kb, Vt transposed)
template <int K, int N, int EPI, bool CONVA>
__global__ __launch_bounds__(256) void gemm_bf16(
    const void* __restrict__ Av, const u16* __restrict__ WT,
    const float* __restrict__ bias,
    u16* __restrict__ O0, u16* __restrict__ O1, u16* __restrict__ O2) {
  __shared__ u16 lds_a[64 * 136];
  __shared__ u16 lds_b[64 * 136];
  const int m0 = blockIdx.x * 64, n0 = blockIdx.y * 64;
  const int tid = threadIdx.x, lane = tid & 63, wv = tid >> 6;
  const int wm = wv >> 1, wn = wv & 1, c = lane & 15, g = lane >> 4;

  f32x4 acc[2][2] = {};
  for (int kt = 0; kt < K / 128; ++kt) {
    if (kt) __syncthreads();
    for (int i = tid; i < 1024; i += 256) {
      int row = i >> 4, cc = (i & 15) * 8;
      if constexpr (CONVA) {
        const float* Af = (const float*)Av;
        const float4* pa =
            (const float4*)(Af + (size_t)(m0 + row) * K + kt * 128 + cc);
        float4 v0 = pa[0], v1 = pa[1];
        uint4 aw = {pk2(v0.x, v0.y), pk2(v0.z, v0.w), pk2(v1.x, v1.y),
                    pk2(v1.z, v1.w)};
        *(uint4*)(&lds_a[row * 136 + cc]) = aw;
      } else {
        const u16* Au = (const u16*)Av;
        *(uint4*)(&lds_a[row * 136 + cc]) =
            *(const uint4*)(Au + (size_t)(m0 + row) * K + kt * 128 + cc);
      }
      *(uint4*)(&lds_b[row * 136 + cc]) =
          *(const uint4*)(WT + (size_t)(n0 + row) * K + kt * 128 + cc);
    }
    __syncthreads();
#pragma unroll
    for (int ks = 0; ks < 4; ++ks) {
      bf16x8 a0 = *(bf16x8*)(&lds_a[(wm * 32 + c) * 136 + ks * 32 + 8 * g]);
      bf16x8 a1 = *(bf16x8*)(&lds_a[(wm * 32 + 16 + c) * 136 + ks * 32 + 8 * g]);
      bf16x8 b0 = *(bf16x8*)(&lds_b[(wn * 32 + c) * 136 + ks * 32 + 8 * g]);
      bf16x8 b1 = *(bf16x8*)(&lds_b[(wn * 32 + 16 + c) * 136 + ks * 32 + 8 * g]);
      acc[0][0] = mfma16(a0, b0, acc[0][0]);
      acc[0][1] = mfma16(a0, b1, acc[0][1]);
      acc[1][0] = mfma16(a1, b0, acc[1][0]);
      acc[1][1] = mfma16(a1, b1, acc[1][1]);
    }
  }
#pragma unroll
  for (int mi = 0; mi < 2; ++mi)
#pragma unroll
    for (int ni = 0; ni < 2; ++ni) {
      const int n = n0 + wn * 32 + ni * 16 + c;
      const int mb = m0 + wm * 32 + mi * 16 + 4 * g;
      if constexpr (EPI == 2) {
        float bv = bias[n];
#pragma unroll
        for (int r = 0; r < 4; ++r)
          O0[(size_t)(mb + r) * N + n] =
              (u16)bfr(fmaxf(acc[mi][ni][r] + bv, 0.f));
      } else {  // EPI == 3
        const int reg = n >> 7, hh = (n >> 5) & 3, d = n & 31;
        const int l = mb >> 11, s = mb & 2047;
        const size_t lh = (size_t)l * 4 + hh;
        if (reg == 0) {
#pragma unroll
          for (int r = 0; r < 4; ++r)
            O0[(lh * 2048 + s + r) * 32 + d] =
                (u16)bfr(acc[mi][ni][r] * 0.17677669529663687f);
        } else if (reg == 1) {
#pragma unroll
          for (int r = 0; r < 4; ++r)
            O1[(lh * 2048 + s + r) * 32 + d] = (u16)bfr(acc[mi][ni][r]);
        } else {
          uint2 w = {pk2(acc[mi][ni][0], acc[mi][ni][1]),
                     pk2(acc[mi][ni][2], acc[mi][ni][3])};
          *(uint2*)(O2 + (lh * 32 + d) * 2048 + s) = w;
        }
      }
    }
}

// ---------------------------------------------- fused GEMM(+bias/relu)+res+LN
template <int K, bool RELU>
__global__ __launch_bounds__(256) void gemm_ln(
    const u16* __restrict__ A, const u16* __restrict__ WT,
    const float* __restrict__ bias, const float* __restrict__ resid,
    const float* __restrict__ gain, const float* __restrict__ lnb,
    float* __restrict__ outf, u16* __restrict__ outb) {
  __shared__ u16 lds_a[64 * 136];
  __shared__ u16 lds_b[128 * 136];
  const int m0 = blockIdx.x * 64;
  const int tid = threadIdx.x, lane = tid & 63, wv = tid >> 6;
  const int c = lane & 15, g = lane >> 4;

  f32x4 acc[8] = {};
  for (int kt = 0; kt < K / 128; ++kt) {
    if (kt) __syncthreads();
    for (int i = tid; i < 1024; i += 256) {
      int row = i >> 4, cc = (i & 15) * 8;
      *(uint4*)(&lds_a[row * 136 + cc]) =
          *(const uint4*)(A + (size_t)(m0 + row) * K + kt * 128 + cc);
    }
    for (int i = tid; i < 2048; i += 256) {
      int row = i >> 4, cc = (i & 15) * 8;
      *(uint4*)(&lds_b[row * 136 + cc]) =
          *(const uint4*)(WT + (size_t)row * K + kt * 128 + cc);
    }
    __syncthreads();
#pragma unroll
    for (int ks = 0; ks < 4; ++ks) {
      bf16x8 a = *(bf16x8*)(&lds_a[(wv * 16 + c) * 136 + ks * 32 + 8 * g]);
#pragma unroll
      for (int ni = 0; ni < 8; ++ni) {
        bf16x8 b = *(bf16x8*)(&lds_b[(ni * 16 + c) * 136 + ks * 32 + 8 * g]);
        acc[ni] = mfma16(a, b, acc[ni]);
      }
    }
  }
  const int rbase = m0 + wv * 16 + 4 * g;
  float gv[8], lb[8], bv[8];
#pragma unroll
  for (int ni = 0; ni < 8; ++ni) {
    gv[ni] = gain[ni * 16 + c];
    lb[ni] = lnb[ni * 16 + c];
    if constexpr (RELU) bv[ni] = bias[ni * 16 + c];
  }
  float t[8][4];
  float sum[4] = {0.f, 0.f, 0.f, 0.f}, sq[4] = {0.f, 0.f, 0.f, 0.f};
#pragma unroll
  for (int ni = 0; ni < 8; ++ni) {
#pragma unroll
    for (int r = 0; r < 4; ++r) {
      float v = acc[ni][r];
      if constexpr (RELU) v = fmaxf(v + bv[ni], 0.f);
      v += resid[(size_t)(rbase + r) * 128 + ni * 16 + c];
      t[ni][r] = v;
      sum[r] += v;
      sq[r] += v * v;
    }
  }
#pragma unroll
  for (int off = 1; off < 16; off <<= 1) {
#pragma unroll
    for (int r = 0; r < 4; ++r) {
      sum[r] += __shfl_xor(sum[r], off);
      sq[r] += __shfl_xor(sq[r], off);
    }
  }
#pragma unroll
  for (int r = 0; r < 4; ++r) {
    float mean = sum[r] * (1.0f / 128.0f);
    float var = sq[r] * (1.0f / 128.0f) - mean * mean;
    float inv = rsqrtf(var + 1e-5f);
#pragma unroll
    for (int ni = 0; ni < 8; ++ni) {
      float o = gv[ni] * (t[ni][r] - mean) * inv + lb[ni];
      outf[(size_t)(rbase + r) * 128 + ni * 16 + c] = o;
      if (outb) outb[(size_t)(rbase + r) * 128 + ni * 16 + c] = (u16)bfr(o);
    }
  }
}

// ---------------------------------------------------------------- attention
// R11 attn4 inner loop VERBATIM (p[16] array-then-pack, f32 lsum, __expf,
// sequential max chain). Split-K: blockIdx.y = split processes 16 of 32
// K-tiles; epilogue writes unnormalized partials (acc, m, lsum) for combine.
__global__ __launch_bounds__(256) void attn4s(
    const u16* __restrict__ Qs, const u16* __restrict__ Kb,
    const u16* __restrict__ Vt, const int* __restrict__ mask,
    const int* __restrict__ mflag, float* __restrict__ Opart,
    float2* __restrict__ ml) {
  __shared__ u16 lds_k[2][64 * 40];   // [key][d]
  __shared__ u16 lds_vt[2][32 * 72];  // [d][key]
  __shared__ u16 lds_p[4][16 * 72];   // per-wave P [q][key 0..63] stride 72
  __shared__ float lds_mk[2][64];

  const int bid = blockIdx.x;
  const int sp = blockIdx.y;           // split 0/1
  const int tbase = sp * 16;           // first K-tile of this split
  const int qt = bid & 31, lh = bid >> 5;
  const int tid = threadIdx.x, lane = tid & 63, wv = tid >> 6;
  const int c = lane & 15, g = lane >> 4;
  const int tok0 = (lh >> 2) * 2048;
  const int allone = mflag[lh >> 2];

  const int qrow = qt * 64 + wv * 16 + c;
  const bf16x8 qf = *(const bf16x8*)(Qs + ((size_t)lh * 2048 + qrow) * 32 + 8 * g);
  const float mq = allone ? 1.0f : (float)mask[tok0 + qrow];

  const int kr_ = tid & 63, kc_ = tid >> 6;  // K stage: row, 16B chunk
  const int vr_ = tid >> 3, vc_ = tid & 7;   // V stage: row(d), 16B chunk
  const u16* kbase = Kb + ((size_t)lh * 2048) * 32 + kr_ * 32 + kc_ * 8;
  const u16* vbase = Vt + ((size_t)lh * 32 + vr_) * 2048 + vc_ * 8;

  uint4 krg, vrg;
  float mkv = 0.f;
  auto issue = [&](int kt0) {
    krg = *(const uint4*)(kbase + (size_t)kt0 * 32);
    vrg = *(const uint4*)(vbase + kt0);
    if (!allone && tid < 64) mkv = (float)mask[tok0 + kt0 + tid];
  };
  auto commit = [&](int buf) {
    *(uint4*)(&lds_k[buf][kr_ * 40 + kc_ * 8]) = krg;
    *(uint4*)(&lds_vt[buf][vr_ * 72 + vc_ * 8]) = vrg;
    if (!allone && tid < 64) lds_mk[buf][tid] = mkv;
  };

  issue(tbase * 64);
  commit(0);
  __syncthreads();

  f32x4 acc0 = {0.f, 0.f, 0.f, 0.f}, acc1 = {0.f, 0.f, 0.f, 0.f};
  float m_run = -1e30f, lsum = 0.f;
  const f32x4 zf = {0.f, 0.f, 0.f, 0.f};

  for (int t = 0; t < 16; ++t) {
    const int cur = t & 1;
    if (t < 15) issue((tbase + t + 1) * 64);

    // QK^T -> S^T (row=key via reg, col=q via lane)
    f32x4 s[4];
#pragma unroll
    for (int j = 0; j < 4; ++j) {
      bf16x8 a = *(bf16x8*)(&lds_k[cur][(16 * j + c) * 40 + 8 * g]);
      s[j] = mfma16(a, qf, zf);
    }
    // faithful mask: am*sc + (am-1)*(-1e9)  -- NO algebraic refactor:
    // (sc-1e9)+1e9 quantizes sc to f32-ulp(1e9)=64 (round-3 bug).
    float sv[16];
    if (allone) {
#pragma unroll
      for (int j = 0; j < 4; ++j)
#pragma unroll
        for (int r = 0; r < 4; ++r) sv[4 * j + r] = s[j][r];
    } else {
#pragma unroll
      for (int j = 0; j < 4; ++j) {
        float4 mk4 = *(float4*)(&lds_mk[cur][16 * j + 4 * g]);  // broadcast
        const float* mkp = (const float*)&mk4;
#pragma unroll
        for (int r = 0; r < 4; ++r) {
          float am = mq * mkp[r];
          sv[4 * j + r] = am * s[j][r] + (am - 1.0f) * (-1e9f);
        }
      }
    }
    float tmax = sv[0];
#pragma unroll
    for (int i = 1; i < 16; ++i) tmax = fmaxf(tmax, sv[i]);
    tmax = fmaxf(tmax, __shfl_xor(tmax, 16));
    tmax = fmaxf(tmax, __shfl_xor(tmax, 32));
    if (!__all(tmax <= m_run + 8.0f)) {  // defer-max (T13)
      float mnew = fmaxf(m_run, tmax);
      float corr = __expf(m_run - mnew);
      m_run = mnew;
      lsum *= corr;
      acc0 *= corr;
      acc1 *= corr;
    }
    float p[16], psum = 0.f;
#pragma unroll
    for (int i = 0; i < 16; ++i) {
      p[i] = __expf(sv[i] - m_run);
      psum += p[i];
    }
    lsum += psum;
    // pack P (keys 16j+4g+r) -> per-wave LDS bounce to B-frag layout
#pragma unroll
    for (int j = 0; j < 4; ++j) {
      uint2 w = {cvtpk(p[4 * j], p[4 * j + 1]), cvtpk(p[4 * j + 2], p[4 * j + 3])};
      *(uint2*)(&lds_p[wv][c * 72 + 16 * j + 4 * g]) = w;
    }
    bf16x8 pb0 = *(bf16x8*)(&lds_p[wv][c * 72 + 8 * g]);
    bf16x8 pb1 = *(bf16x8*)(&lds_p[wv][c * 72 + 32 + 8 * g]);
    bf16x8 v00 = *(bf16x8*)(&lds_vt[cur][c * 72 + 8 * g]);
    bf16x8 v01 = *(bf16x8*)(&lds_vt[cur][c * 72 + 32 + 8 * g]);
    bf16x8 v10 = *(bf16x8*)(&lds_vt[cur][(16 + c) * 72 + 8 * g]);
    bf16x8 v11 = *(bf16x8*)(&lds_vt[cur][(16 + c) * 72 + 32 + 8 * g]);
    acc0 = mfma16(v00, pb0, acc0);
    acc0 = mfma16(v01, pb1, acc0);
    acc1 = mfma16(v10, pb0, acc1);
    acc1 = mfma16(v11, pb1, acc1);

    if (t < 15) commit(cur ^ 1);
    __syncthreads();
  }
  float lt = lsum;
  lt += __shfl_xor(lt, 16);
  lt += __shfl_xor(lt, 32);
  // partial epilogue: unnormalized acc (f32) + (m_run, lt) per q-row
  float* op = Opart + (size_t)sp * 2097152 + ((size_t)lh * 2048 + qrow) * 32;
  float4 o0 = {acc0[0], acc0[1], acc0[2], acc0[3]};
  float4 o1 = {acc1[0], acc1[1], acc1[2], acc1[3]};
  *(float4*)(op + 4 * g) = o0;
  *(float4*)(op + 16 + 4 * g) = o1;
  if (lane < 16) {
    float2 v = {m_run, lt};
    ml[(size_t)sp * 65536 + (size_t)lh * 2048 + qrow] = v;
  }
}

// ------------------------------------------------- split-K softmax combine
// out[(tok,h,d)] = (w0*O0 + w1*O1) / (w0*l0 + w1*l1), wi = exp(mi - max(m)).
__global__ __launch_bounds__(256) void attn_combine(
    const float* __restrict__ Opart, const float2* __restrict__ ml,
    u16* __restrict__ ctx) {
  int idx = blockIdx.x * 256 + threadIdx.x;  // 2M = 32 lh * 2048 q * 32 d
  int lhq = idx >> 5, d = idx & 31;
  int lh = lhq >> 11, qrow = lhq & 2047;
  float2 a = ml[lhq], b = ml[65536 + lhq];
  float M = fmaxf(a.x, b.x);
  float w0 = __expf(a.x - M), w1 = __expf(b.x - M);
  float L = w0 * a.y + w1 * b.y;
  float o = (w0 * Opart[idx] + w1 * Opart[2097152 + idx]) / L;
  int tok = (lh >> 2) * 2048 + qrow, h = lh & 3;
  ctx[(size_t)tok * 128 + h * 32 + d] = (u16)bfr(o);
}

// ---------------------------------------------------------------- launch
extern "C" void kernel_launch(void* const* d_in, const int* in_sizes, int n_in,
                              void* d_out, int out_size, void* d_ws,
                              size_t ws_size, hipStream_t stream) {
  (void)in_sizes; (void)n_in; (void)out_size; (void)ws_size;
  const float* x = (const float*)d_in[0];
  const int* mask = (const int*)d_in[1];
  const float* qkv_w = (const float*)d_in[2];
  const float* out_w = (const float*)d_in[3];
  const float* w1 = (const float*)d_in[4];
  const float* b1 = (const float*)d_in[5];
  const float* w2 = (const float*)d_in[6];
  const float* b2 = (const float*)d_in[7];
  const float* g1 = (const float*)d_in[8];
  const float* be1 = (const float*)d_in[9];
  const float* g2 = (const float*)d_in[10];
  const float* be2 = (const float*)d_in[11];
  float* out = (float*)d_out;

  char* ws = (char*)d_ws;
  const size_t MB = 1 << 20;
  // [0,12): Qs|Kb|Vt ; after attn reused as ff_bf (exactly 12 MB)
  u16* Qs = (u16*)(ws);
  u16* Kb = (u16*)(ws + 4 * MB);
  u16* Vt = (u16*)(ws + 8 * MB);
  u16* ff_bf = (u16*)(ws);
  u16* ctx_bf = (u16*)(ws + 12 * MB);  // [12,16)
  // [16,32): Opart (2 splits x 8MB) during attn; then h [16,24) + h_bf [24,28)
  float* Opart = (float*)(ws + 16 * MB);
  float* h = (float*)(ws + 16 * MB);
  u16* h_bf = (u16*)(ws + 24 * MB);
  u16* qkvT = (u16*)(ws + 32 * MB);
  u16* outT = qkvT + 384 * 128;
  u16* w1T = outT + 128 * 128;
  u16* w2T = w1T + 384 * 128;
  int* mflag = (int*)(ws + 33 * MB);
  float2* ml = (float2*)(ws + 34 * MB);  // [34,35): 2 x 64K float2

  prep_all<<<648, 256, 0, stream>>>(qkv_w, out_w, w1, w2, mask, qkvT, outT,
                                    w1T, w2T, mflag);
  gemm_bf16<128, 384, 3, true><<<dim3(256, 6), 256, 0, stream>>>(
      (const void*)x, qkvT, nullptr, Qs, Kb, Vt);
  attn4s<<<dim3(1024, 2), 256, 0, stream>>>(Qs, Kb, Vt, mask, mflag, Opart, ml);
  attn_combine<<<8192, 256, 0, stream>>>(Opart, ml, ctx_bf);
  gemm_ln<128, false><<<256, 256, 0, stream>>>(
      ctx_bf, outT, nullptr, x, g1, be1, h, h_bf);
  gemm_bf16<128, 384, 2, false><<<dim3(256, 6), 256, 0, stream>>>(
      (const void*)h_bf, w1T, b1, ff_bf, nullptr, nullptr);
  gemm_ln<384, true><<<256, 256, 0, stream>>>(
      ff_bf, w2T, b2, h, g2, be2, out, nullptr);
}

// Round 15
// 96.889 us; speedup vs baseline: 1.1033x; 1.0971x over previous
//
#include <hip/hip_runtime.h>
#include <hip/hip_bf16.h>

typedef __attribute__((ext_vector_type(8))) short bf16x8;
typedef __attribute__((ext_vector_type(4))) float f32x4;
typedef unsigned short u16;
typedef unsigned int u32;

__device__ __forceinline__ u32 bfr(float x) {
  u32 u = __float_as_uint(x);
  return (u + 0x7fffu + ((u >> 16) & 1u)) >> 16;  // RNE f32 -> bf16 bits
}
__device__ __forceinline__ u32 pk2(float lo, float hi) {
  return bfr(lo) | (bfr(hi) << 16);
}
__device__ __forceinline__ u32 cvtpk(float lo, float hi) {
  u32 r;
  asm("v_cvt_pk_bf16_f32 %0, %1, %2" : "=v"(r) : "v"(lo), "v"(hi));
  return r;
}

__device__ __forceinline__ f32x4 mfma16(bf16x8 a, bf16x8 b, f32x4 c) {
  return __builtin_amdgcn_mfma_f32_16x16x32_bf16(a, b, c, 0, 0, 0);
}

// ------------------------------------------------- combined prep (weights+mask)
__global__ __launch_bounds__(256) void prep_all(
    const float* __restrict__ qkv_w, const float* __restrict__ out_w,
    const float* __restrict__ w1, const float* __restrict__ w2,
    const int* __restrict__ mask,
    u16* __restrict__ qkvT, u16* __restrict__ outT,
    u16* __restrict__ w1T, u16* __restrict__ w2T, int* __restrict__ flag) {
  __shared__ int wbad[4];
  int b = blockIdx.x;
  if (b >= 640) {
    int l = b - 640;
    int bad = 0;
    for (int i = threadIdx.x; i < 2048; i += 256)
      bad |= (mask[l * 2048 + i] != 1);
    unsigned long long bl = __ballot(bad != 0);
    if ((threadIdx.x & 63) == 0) wbad[threadIdx.x >> 6] = (bl != 0ULL) ? 1 : 0;
    __syncthreads();
    if (threadIdx.x == 0)
      flag[l] = (wbad[0] | wbad[1] | wbad[2] | wbad[3]) ? 0 : 1;
    return;
  }
  int idx = b * 256 + threadIdx.x;
  if (idx < 49152) {
    int n = idx >> 7, k = idx & 127;
    qkvT[idx] = (u16)bfr(qkv_w[k * 384 + n]);
  } else if (idx < 49152 + 16384) {
    int i = idx - 49152;
    int n = i >> 7, k = i & 127;
    outT[i] = (u16)bfr(out_w[k * 128 + n]);
  } else if (idx < 49152 + 16384 + 49152) {
    int i = idx - 49152 - 16384;
    int n = i >> 7, k = i & 127;
    w1T[i] = (u16)bfr(w1[k * 384 + n]);
  } else if (idx < 163840) {
    int i = idx - 49152 - 16384 - 49152;
    int n = i / 384, k = i - n * 384;
    w2T[i] = (u16)bfr(w2[k * 128 + n]);
  }
}

// ---------------------------------------------------------------- generic GEMM
// R11-exact. CONVA: A f32 -> bf16 during staging. EPI 2 = bias+relu bf16 ;
// EPI 3 = qkv epilogue (Qs scaled by 1/sqrt(32), Kb, Vt transposed)
template <int K, int N, int EPI, bool CONVA>
__global__ __launch_bounds__(256) void gemm_bf16(
    const void* __restrict__ Av, const u16* __restrict__ WT,
    const float* __restrict__ bias,
    u16* __restrict__ O0, u16* __restrict__ O1, u16* __restrict__ O2) {
  __shared__ u16 lds_a[64 * 136];
  __shared__ u16 lds_b[64 * 136];
  const int m0 = blockIdx.x * 64, n0 = blockIdx.y * 64;
  const int tid = threadIdx.x, lane = tid & 63, wv = tid >> 6;
  const int wm = wv >> 1, wn = wv & 1, c = lane & 15, g = lane >> 4;

  f32x4 acc[2][2] = {};
  for (int kt = 0; kt < K / 128; ++kt) {
    if (kt) __syncthreads();
    for (int i = tid; i < 1024; i += 256) {
      int row = i >> 4, cc = (i & 15) * 8;
      if constexpr (CONVA) {
        const float* Af = (const float*)Av;
        const float4* pa =
            (const float4*)(Af + (size_t)(m0 + row) * K + kt * 128 + cc);
        float4 v0 = pa[0], v1 = pa[1];
        uint4 aw = {pk2(v0.x, v0.y), pk2(v0.z, v0.w), pk2(v1.x, v1.y),
                    pk2(v1.z, v1.w)};
        *(uint4*)(&lds_a[row * 136 + cc]) = aw;
      } else {
        const u16* Au = (const u16*)Av;
        *(uint4*)(&lds_a[row * 136 + cc]) =
            *(const uint4*)(Au + (size_t)(m0 + row) * K + kt * 128 + cc);
      }
      *(uint4*)(&lds_b[row * 136 + cc]) =
          *(const uint4*)(WT + (size_t)(n0 + row) * K + kt * 128 + cc);
    }
    __syncthreads();
#pragma unroll
    for (int ks = 0; ks < 4; ++ks) {
      bf16x8 a0 = *(bf16x8*)(&lds_a[(wm * 32 + c) * 136 + ks * 32 + 8 * g]);
      bf16x8 a1 = *(bf16x8*)(&lds_a[(wm * 32 + 16 + c) * 136 + ks * 32 + 8 * g]);
      bf16x8 b0 = *(bf16x8*)(&lds_b[(wn * 32 + c) * 136 + ks * 32 + 8 * g]);
      bf16x8 b1 = *(bf16x8*)(&lds_b[(wn * 32 + 16 + c) * 136 + ks * 32 + 8 * g]);
      acc[0][0] = mfma16(a0, b0, acc[0][0]);
      acc[0][1] = mfma16(a0, b1, acc[0][1]);
      acc[1][0] = mfma16(a1, b0, acc[1][0]);
      acc[1][1] = mfma16(a1, b1, acc[1][1]);
    }
  }
#pragma unroll
  for (int mi = 0; mi < 2; ++mi)
#pragma unroll
    for (int ni = 0; ni < 2; ++ni) {
      const int n = n0 + wn * 32 + ni * 16 + c;
      const int mb = m0 + wm * 32 + mi * 16 + 4 * g;
      if constexpr (EPI == 2) {
        float bv = bias[n];
#pragma unroll
        for (int r = 0; r < 4; ++r)
          O0[(size_t)(mb + r) * N + n] =
              (u16)bfr(fmaxf(acc[mi][ni][r] + bv, 0.f));
      } else {  // EPI == 3
        const int reg = n >> 7, hh = (n >> 5) & 3, d = n & 31;
        const int l = mb >> 11, s = mb & 2047;
        const size_t lh = (size_t)l * 4 + hh;
        if (reg == 0) {
#pragma unroll
          for (int r = 0; r < 4; ++r)
            O0[(lh * 2048 + s + r) * 32 + d] =
                (u16)bfr(acc[mi][ni][r] * 0.17677669529663687f);
        } else if (reg == 1) {
#pragma unroll
          for (int r = 0; r < 4; ++r)
            O1[(lh * 2048 + s + r) * 32 + d] = (u16)bfr(acc[mi][ni][r]);
        } else {
          uint2 w = {pk2(acc[mi][ni][0], acc[mi][ni][1]),
                     pk2(acc[mi][ni][2], acc[mi][ni][3])};
          *(uint2*)(O2 + (lh * 32 + d) * 2048 + s) = w;
        }
      }
    }
}

// ---------------------------------------------- fused GEMM(+bias/relu)+res+LN
// RESB: resid is bf16 (exact shift to f32). outf/outb each nullable.
template <int K, bool RELU, bool RESB>
__global__ __launch_bounds__(256) void gemm_ln(
    const u16* __restrict__ A, const u16* __restrict__ WT,
    const float* __restrict__ bias, const void* __restrict__ residv,
    const float* __restrict__ gain, const float* __restrict__ lnb,
    float* __restrict__ outf, u16* __restrict__ outb) {
  __shared__ u16 lds_a[64 * 136];
  __shared__ u16 lds_b[128 * 136];
  const int m0 = blockIdx.x * 64;
  const int tid = threadIdx.x, lane = tid & 63, wv = tid >> 6;
  const int c = lane & 15, g = lane >> 4;

  f32x4 acc[8] = {};
  for (int kt = 0; kt < K / 128; ++kt) {
    if (kt) __syncthreads();
    for (int i = tid; i < 1024; i += 256) {
      int row = i >> 4, cc = (i & 15) * 8;
      *(uint4*)(&lds_a[row * 136 + cc]) =
          *(const uint4*)(A + (size_t)(m0 + row) * K + kt * 128 + cc);
    }
    for (int i = tid; i < 2048; i += 256) {
      int row = i >> 4, cc = (i & 15) * 8;
      *(uint4*)(&lds_b[row * 136 + cc]) =
          *(const uint4*)(WT + (size_t)row * K + kt * 128 + cc);
    }
    __syncthreads();
#pragma unroll
    for (int ks = 0; ks < 4; ++ks) {
      bf16x8 a = *(bf16x8*)(&lds_a[(wv * 16 + c) * 136 + ks * 32 + 8 * g]);
#pragma unroll
      for (int ni = 0; ni < 8; ++ni) {
        bf16x8 b = *(bf16x8*)(&lds_b[(ni * 16 + c) * 136 + ks * 32 + 8 * g]);
        acc[ni] = mfma16(a, b, acc[ni]);
      }
    }
  }
  const int rbase = m0 + wv * 16 + 4 * g;
  float gv[8], lb[8], bv[8];
#pragma unroll
  for (int ni = 0; ni < 8; ++ni) {
    gv[ni] = gain[ni * 16 + c];
    lb[ni] = lnb[ni * 16 + c];
    if constexpr (RELU) bv[ni] = bias[ni * 16 + c];
  }
  float t[8][4];
  float sum[4] = {0.f, 0.f, 0.f, 0.f}, sq[4] = {0.f, 0.f, 0.f, 0.f};
#pragma unroll
  for (int ni = 0; ni < 8; ++ni) {
#pragma unroll
    for (int r = 0; r < 4; ++r) {
      float v = acc[ni][r];
      if constexpr (RELU) v = fmaxf(v + bv[ni], 0.f);
      size_t idx = (size_t)(rbase + r) * 128 + ni * 16 + c;
      float rv;
      if constexpr (RESB) {
        rv = __uint_as_float((u32)((const u16*)residv)[idx] << 16);
      } else {
        rv = ((const float*)residv)[idx];
      }
      v += rv;
      t[ni][r] = v;
      sum[r] += v;
      sq[r] += v * v;
    }
  }
#pragma unroll
  for (int off = 1; off < 16; off <<= 1) {
#pragma unroll
    for (int r = 0; r < 4; ++r) {
      sum[r] += __shfl_xor(sum[r], off);
      sq[r] += __shfl_xor(sq[r], off);
    }
  }
#pragma unroll
  for (int r = 0; r < 4; ++r) {
    float mean = sum[r] * (1.0f / 128.0f);
    float var = sq[r] * (1.0f / 128.0f) - mean * mean;
    float inv = rsqrtf(var + 1e-5f);
#pragma unroll
    for (int ni = 0; ni < 8; ++ni) {
      float o = gv[ni] * (t[ni][r] - mean) * inv + lb[ni];
      size_t idx = (size_t)(rbase + r) * 128 + ni * 16 + c;
      if (outf) outf[idx] = o;
      if (outb) outb[idx] = (u16)bfr(o);
    }
  }
}

// ---------------------------------------------------------------- attention
// VERBATIM R11 attn4 (passed, 56.0 us): all-ones fast path guarded inside,
// cross-lane tmax defer, f32 lsum, __expf, KT=64 dbuf, P ARRAY-then-pack
// (empirical rule: inline P pack fails R5/R9/R10/R12; array pack passes
// R4/R6/R7/R8/R11/R13/R14).
__global__ __launch_bounds__(256) void attn4(
    const u16* __restrict__ Qs, const u16* __restrict__ Kb,
    const u16* __restrict__ Vt, const int* __restrict__ mask,
    const int* __restrict__ mflag, u16* __restrict__ ctx) {
  __shared__ u16 lds_k[2][64 * 40];   // [key][d]
  __shared__ u16 lds_vt[2][32 * 72];  // [d][key]
  __shared__ u16 lds_p[4][16 * 72];   // per-wave P [q][key 0..63] stride 72
  __shared__ float lds_mk[2][64];

  const int bid = blockIdx.x;
  const int qt = bid & 31, lh = bid >> 5;
  const int tid = threadIdx.x, lane = tid & 63, wv = tid >> 6;
  const int c = lane & 15, g = lane >> 4;
  const int tok0 = (lh >> 2) * 2048;
  const int h = lh & 3;
  const int allone = mflag[lh >> 2];

  const int qrow = qt * 64 + wv * 16 + c;
  const bf16x8 qf = *(const bf16x8*)(Qs + ((size_t)lh * 2048 + qrow) * 32 + 8 * g);
  const float mq = allone ? 1.0f : (float)mask[tok0 + qrow];

  const int kr_ = tid & 63, kc_ = tid >> 6;  // K stage: row, 16B chunk
  const int vr_ = tid >> 3, vc_ = tid & 7;   // V stage: row(d), 16B chunk
  const u16* kbase = Kb + ((size_t)lh * 2048) * 32 + kr_ * 32 + kc_ * 8;
  const u16* vbase = Vt + ((size_t)lh * 32 + vr_) * 2048 + vc_ * 8;

  uint4 krg, vrg;
  float mkv = 0.f;
  auto issue = [&](int kt0) {
    krg = *(const uint4*)(kbase + (size_t)kt0 * 32);
    vrg = *(const uint4*)(vbase + kt0);
    if (!allone && tid < 64) mkv = (float)mask[tok0 + kt0 + tid];
  };
  auto commit = [&](int buf) {
    *(uint4*)(&lds_k[buf][kr_ * 40 + kc_ * 8]) = krg;
    *(uint4*)(&lds_vt[buf][vr_ * 72 + vc_ * 8]) = vrg;
    if (!allone && tid < 64) lds_mk[buf][tid] = mkv;
  };

  issue(0);
  commit(0);
  __syncthreads();

  f32x4 acc0 = {0.f, 0.f, 0.f, 0.f}, acc1 = {0.f, 0.f, 0.f, 0.f};
  float m_run = -1e30f, lsum = 0.f;
  const f32x4 zf = {0.f, 0.f, 0.f, 0.f};

  for (int t = 0; t < 32; ++t) {
    const int cur = t & 1;
    if (t < 31) issue((t + 1) * 64);

    // QK^T -> S^T (row=key via reg, col=q via lane)
    f32x4 s[4];
#pragma unroll
    for (int j = 0; j < 4; ++j) {
      bf16x8 a = *(bf16x8*)(&lds_k[cur][(16 * j + c) * 40 + 8 * g]);
      s[j] = mfma16(a, qf, zf);
    }
    // faithful mask: am*sc + (am-1)*(-1e9)  -- NO algebraic refactor:
    // (sc-1e9)+1e9 quantizes sc to f32-ulp(1e9)=64 (round-3 bug).
    float sv[16];
    if (allone) {
#pragma unroll
      for (int j = 0; j < 4; ++j)
#pragma unroll
        for (int r = 0; r < 4; ++r) sv[4 * j + r] = s[j][r];
    } else {
#pragma unroll
      for (int j = 0; j < 4; ++j) {
        float4 mk4 = *(float4*)(&lds_mk[cur][16 * j + 4 * g]);  // broadcast
        const float* mkp = (const float*)&mk4;
#pragma unroll
        for (int r = 0; r < 4; ++r) {
          float am = mq * mkp[r];
          sv[4 * j + r] = am * s[j][r] + (am - 1.0f) * (-1e9f);
        }
      }
    }
    float tmax = sv[0];
#pragma unroll
    for (int i = 1; i < 16; ++i) tmax = fmaxf(tmax, sv[i]);
    tmax = fmaxf(tmax, __shfl_xor(tmax, 16));
    tmax = fmaxf(tmax, __shfl_xor(tmax, 32));
    if (!__all(tmax <= m_run + 8.0f)) {  // defer-max (T13)
      float mnew = fmaxf(m_run, tmax);
      float corr = __expf(m_run - mnew);
      m_run = mnew;
      lsum *= corr;
      acc0 *= corr;
      acc1 *= corr;
    }
    float p[16], psum = 0.f;
#pragma unroll
    for (int i = 0; i < 16; ++i) {
      p[i] = __expf(sv[i] - m_run);
      psum += p[i];
    }
    lsum += psum;
    // pack P (keys 16j+4g+r) -> per-wave LDS bounce to B-frag layout
#pragma unroll
    for (int j = 0; j < 4; ++j) {
      uint2 w = {cvtpk(p[4 * j], p[4 * j + 1]), cvtpk(p[4 * j + 2], p[4 * j + 3])};
      *(uint2*)(&lds_p[wv][c * 72 + 16 * j + 4 * g]) = w;
    }
    bf16x8 pb0 = *(bf16x8*)(&lds_p[wv][c * 72 + 8 * g]);
    bf16x8 pb1 = *(bf16x8*)(&lds_p[wv][c * 72 + 32 + 8 * g]);
    bf16x8 v00 = *(bf16x8*)(&lds_vt[cur][c * 72 + 8 * g]);
    bf16x8 v01 = *(bf16x8*)(&lds_vt[cur][c * 72 + 32 + 8 * g]);
    bf16x8 v10 = *(bf16x8*)(&lds_vt[cur][(16 + c) * 72 + 8 * g]);
    bf16x8 v11 = *(bf16x8*)(&lds_vt[cur][(16 + c) * 72 + 32 + 8 * g]);
    acc0 = mfma16(v00, pb0, acc0);
    acc0 = mfma16(v01, pb1, acc0);
    acc1 = mfma16(v10, pb0, acc1);
    acc1 = mfma16(v11, pb1, acc1);

    if (t < 31) commit(cur ^ 1);
    __syncthreads();
  }
  float lt = lsum;
  lt += __shfl_xor(lt, 16);
  lt += __shfl_xor(lt, 32);
  float inv = 1.0f / lt;
  u16* op = ctx + (size_t)(tok0 + qrow) * 128 + h * 32;
  uint2 o0 = {cvtpk(acc0[0] * inv, acc0[1] * inv),
              cvtpk(acc0[2] * inv, acc0[3] * inv)};
  uint2 o1 = {cvtpk(acc1[0] * inv, acc1[1] * inv),
              cvtpk(acc1[2] * inv, acc1[3] * inv)};
  *(uint2*)(op + 4 * g) = o0;
  *(uint2*)(op + 16 + 4 * g) = o1;
}

// ---------------------------------------------------------------- launch
extern "C" void kernel_launch(void* const* d_in, const int* in_sizes, int n_in,
                              void* d_out, int out_size, void* d_ws,
                              size_t ws_size, hipStream_t stream) {
  (void)in_sizes; (void)n_in; (void)out_size; (void)ws_size;
  const float* x = (const float*)d_in[0];
  const int* mask = (const int*)d_in[1];
  const float* qkv_w = (const float*)d_in[2];
  const float* out_w = (const float*)d_in[3];
  const float* w1 = (const float*)d_in[4];
  const float* b1 = (const float*)d_in[5];
  const float* w2 = (const float*)d_in[6];
  const float* b2 = (const float*)d_in[7];
  const float* g1 = (const float*)d_in[8];
  const float* be1 = (const float*)d_in[9];
  const float* g2 = (const float*)d_in[10];
  const float* be2 = (const float*)d_in[11];
  float* out = (float*)d_out;

  char* ws = (char*)d_ws;
  const size_t MB = 1 << 20;
  // [0,12): Qs|Kb|Vt ; after attn reused as ff_bf (12.6MB, spills into dead
  // ctx_bf region [12,16) -- ctx_bf consumed by gemm_ln<128> before ffn1)
  u16* Qs = (u16*)(ws);
  u16* Kb = (u16*)(ws + 4 * MB);
  u16* Vt = (u16*)(ws + 8 * MB);
  u16* ff_bf = (u16*)(ws);
  u16* ctx_bf = (u16*)(ws + 12 * MB);  // [12,16)
  u16* h_bf = (u16*)(ws + 24 * MB);    // [24,28)
  u16* qkvT = (u16*)(ws + 32 * MB);
  u16* outT = qkvT + 384 * 128;
  u16* w1T = outT + 128 * 128;
  u16* w2T = w1T + 384 * 128;
  int* mflag = (int*)(ws + 33 * MB);

  prep_all<<<648, 256, 0, stream>>>(qkv_w, out_w, w1, w2, mask, qkvT, outT,
                                    w1T, w2T, mflag);
  gemm_bf16<128, 384, 3, true><<<dim3(256, 6), 256, 0, stream>>>(
      (const void*)x, qkvT, nullptr, Qs, Kb, Vt);
  attn4<<<1024, 256, 0, stream>>>(Qs, Kb, Vt, mask, mflag, ctx_bf);
  gemm_ln<128, false, false><<<256, 256, 0, stream>>>(
      ctx_bf, outT, nullptr, (const void*)x, g1, be1, nullptr, h_bf);
  gemm_bf16<128, 384, 2, false><<<dim3(256, 6), 256, 0, stream>>>(
      (const void*)h_bf, w1T, b1, ff_bf, nullptr, nullptr);
  gemm_ln<384, true, true><<<256, 256, 0, stream>>>(
      ff_bf, w2T, b2, (const void*)h_bf, g2, be2, out, nullptr);
}